// Round 3
// baseline (98.039 us; speedup 1.0000x reference)
//
#include <hip/hip_runtime.h>

namespace {
constexpr int N  = 64;
constexpr int D  = 32;
constexpr int PD  = 36;  // padded ind row (dwords): stride-36 measured conflict-free
constexpr int SHP = 68;  // sh row pad (dwords), float4-aligned, 68%32=4 -> <=2-way
constexpr float LOG2E = 1.4426950408889634f;
constexpr float LN2   = 0.6931471805599453f;

__device__ __forceinline__ float fexp2(float x) { return exp2f(x); }  // -> v_exp_f32
__device__ __forceinline__ float frcp(float x) { return __frcp_rn(x) * 1.0f; }

// One block per b (grid 512, block 512 = 8 waves, 62.2 KB LDS -> 2 blocks/CU,
// all 512 blocks resident: zero tail). Wave owns rows i = wave*8..+7 in 2
// groups of 4 (full unroll inside group for softmax ILP).
//
// Single-exp identity (exact):
//   elup1(a)*elup1(b) = exp(min(a,0)+min(b,0)) * (1+max(a,0)) * (1+max(b,0))
// with a,b pre-scaled by log2e so the exp is one v_exp_f32 (exp is ~1/8-rate:
// r1/r2 evidence shows 2 exps/element dominated VALU issue).
__global__ __launch_bounds__(512, 4) void fused(
        const float* __restrict__ feature,
        const float* __restrict__ ind,
        float* __restrict__ out) {
    __shared__ float ind_lds[3][N][PD];    // 27648 B
    __shared__ float s_lds[3][N];          //   768 B
    __shared__ float gate_lds[N][N];       // 16384 B
    __shared__ float sh_lds[N][SHP];       // 17408 B  (total 62208 B)

    const int t    = threadIdx.x;
    const int lane = t & 63;
    const int wave = t >> 6;
    const int b    = blockIdx.x;

    // ---- stage indicator: 1536 float4, 3 per thread, coalesced ----
    {
        const float4* src = reinterpret_cast<const float4*>(ind);
#pragma unroll
        for (int idx = t; idx < 3 * N * D / 4; idx += 512) {
            int a = idx >> 9;
            int r = idx & 511;
            int n = r >> 3;
            int k = r & 7;
            *reinterpret_cast<float4*>(&ind_lds[a][n][k * 4]) = src[idx];
        }
    }
    __syncthreads();

    // ---- phase 1: gate (8 dots/thread) + s (threads < 192) ----
    {
        const int i  = t >> 3;      // [0,64)
        const int jq = t & 7;       // j in {jq, jq+8, ..., jq+56}
        float acc[8] = {0.f, 0.f, 0.f, 0.f, 0.f, 0.f, 0.f, 0.f};
#pragma unroll
        for (int dq = 0; dq < 8; ++dq) {
            float4 a4 = *reinterpret_cast<const float4*>(&ind_lds[0][i][dq * 4]);
#pragma unroll
            for (int c = 0; c < 8; ++c) {
                float4 b4 = *reinterpret_cast<const float4*>(&ind_lds[1][jq + 8 * c][dq * 4]);
                acc[c] += a4.x * b4.x + a4.y * b4.y + a4.z * b4.z + a4.w * b4.w;
            }
        }
#pragma unroll
        for (int c = 0; c < 8; ++c)
            gate_lds[i][jq + 8 * c] = (acc[c] > 0.f) ? 1.f : 0.f;

        if (t < 3 * N) {
            int a = t >> 6, n = t & 63;
            const float4* frow = reinterpret_cast<const float4*>(feature + ((size_t)b * N + n) * D);
            float sa = 0.f;
#pragma unroll
            for (int k = 0; k < 8; ++k) {
                float4 f4 = frow[k];
                float4 i4 = *reinterpret_cast<const float4*>(&ind_lds[a][n][k * 4]);
                sa += f4.x * i4.x + f4.y * i4.y + f4.z * i4.z + f4.w * i4.w;
            }
            s_lds[a][n] = sa;
        }
    }
    __syncthreads();

    // ---- per-lane: u = ind0[lane,:] in 32 VGPRs; s1 pre-scaled ----
    float4 u[8];
#pragma unroll
    for (int k = 0; k < 8; ++k)
        u[k] = *reinterpret_cast<const float4*>(&ind_lds[0][lane][k * 4]);
    const float s1L = s_lds[1][lane] * LOG2E;

    // ---- score + softmax: 2 groups of 4 rows ----
#pragma unroll 1
    for (int g = 0; g < 2; ++g) {
        const int i0 = wave * 8 + g * 4;
        float score[4];
#pragma unroll
        for (int r = 0; r < 4; ++r) {
            const int   ig  = i0 + r;
            const float s0L = s_lds[0][ig] * LOG2E;
            float sc = 0.f;
#pragma unroll
            for (int k = 0; k < 8; ++k) {
                float4 v4 = *reinterpret_cast<const float4*>(&ind_lds[1][ig][k * 4]);  // broadcast
#pragma unroll
                for (int c = 0; c < 4; ++c) {
                    float aL = s0L * (&u[k].x)[c];
                    float bL = s1L * (&v4.x)[c];
                    float E  = fexp2(fminf(aL, 0.f) + fminf(bL, 0.f));
                    float A  = fmaf(fmaxf(aL, 0.f), LN2, 1.0f);
                    float B  = fmaf(fmaxf(bL, 0.f), LN2, 1.0f);
                    sc = fmaf(E * A, B, sc);
                }
            }
            score[r] = sc;
        }

        // 4-way-ILP wave softmax over j (64 lanes)
        float mx[4], e[4], sm[4];
#pragma unroll
        for (int r = 0; r < 4; ++r) mx[r] = score[r];
#pragma unroll
        for (int off = 32; off >= 1; off >>= 1) {
#pragma unroll
            for (int r = 0; r < 4; ++r) mx[r] = fmaxf(mx[r], __shfl_xor(mx[r], off));
        }
#pragma unroll
        for (int r = 0; r < 4; ++r) e[r] = fexp2((score[r] - mx[r]) * LOG2E);
#pragma unroll
        for (int r = 0; r < 4; ++r) sm[r] = e[r];
#pragma unroll
        for (int off = 32; off >= 1; off >>= 1) {
#pragma unroll
            for (int r = 0; r < 4; ++r) sm[r] += __shfl_xor(sm[r], off);
        }
#pragma unroll
        for (int r = 0; r < 4; ++r) {
            const int ig = i0 + r;
            sh_lds[ig][lane] = (e[r] * gate_lds[ig][lane]) * (s_lds[2][ig] / sm[r]);
        }
    }
    __syncthreads();

    // ---- phase 2: out[i,:] = sh[i,:] @ ind2; thread = (i, d-quad) ----
    {
        const int i  = t >> 3;
        const int dq = t & 7;
        float4 acc = {0.f, 0.f, 0.f, 0.f};
#pragma unroll 4
        for (int j = 0; j < N; j += 4) {
            float4 sh4 = *reinterpret_cast<const float4*>(&sh_lds[i][j]);
#pragma unroll
            for (int c = 0; c < 4; ++c) {
                float4 v4 = *reinterpret_cast<const float4*>(&ind_lds[2][j + c][dq * 4]);
                float  w  = (&sh4.x)[c];
                acc.x = fmaf(w, v4.x, acc.x);
                acc.y = fmaf(w, v4.y, acc.y);
                acc.z = fmaf(w, v4.z, acc.z);
                acc.w = fmaf(w, v4.w, acc.w);
            }
        }
        *reinterpret_cast<float4*>(out + ((size_t)b * N + i) * D + dq * 4) = acc;
    }
}
}  // namespace

extern "C" void kernel_launch(void* const* d_in, const int* in_sizes, int n_in,
                              void* d_out, int out_size, void* d_ws, size_t ws_size,
                              hipStream_t stream) {
    const float* feature = (const float*)d_in[0];
    const float* ind     = (const float*)d_in[1];
    float*       out     = (float*)d_out;
    fused<<<512, 512, 0, stream>>>(feature, ind, out);
}